// Round 16
// baseline (93.818 us; speedup 1.0000x reference)
//
#include <hip/hip_runtime.h>
#include <string.h>

#define NUM_PTS 1024
#define NBATCH 128
#define BT 256                       // 4 waves: w = dir + 2*qhalf
#define RT 256
#define NJC 8                        // stored q-chunks per direction (128 pts each)
#define JCH 64                       // points per wave (half chunk)
#define R 16                         // rows per thread (64 lanes x 16 = all 1024)
#define CHAMF_SCALE (1.0f / 1024.0f)
#define KLD_SCALE   (-0.5f * 0.1f / 32.0f)

// ws: float [2][NJC][NBATCH][NUM_PTS] row partials = 8.4 MB.
#define WS_CHUNK (NBATCH * NUM_PTS)          // 131072
#define WS_DIR   (NJC * WS_CHUNK)            // 1048576

typedef _Float16 h2 __attribute__((ext_vector_type(2)));
static __device__ __forceinline__ h2 as_h2(unsigned u) {
    h2 r; memcpy(&r, &u, 4); return r;
}
static __device__ __forceinline__ unsigned as_u32(h2 h) {
    unsigned r; memcpy(&r, &h, 4); return r;
}

// R14 structure; inner loop moved to v_dot2_f32_f16 (exact f16 products,
// fp32 accumulate): d = fdot2(Axy, qxy, fdot2(Az0, qz0, q2)) = 2 insts/eval
// vs fp32's 3.5 (row+q clouds BOTH quantized to f16; q2=|q_hat|^2 and
// r2=|p_hat|^2 in fp32 from quantized values -> d = |p_hat-q_hat|^2 exactly:
// no cancellation, no min-selection bias; err vs ref ~1e-3 << 0.645 thresh).
// VALU floor 12 -> 8.5 us; LDS 4 -> 3 b128 per 4 qpts.
__global__ __launch_bounds__(BT, 2) void chamfer_part(
    const float* __restrict__ recon_x,
    const float* __restrict__ x,
    float* __restrict__ ws,
    float* __restrict__ out)
{
    const int b  = blockIdx.x & 127;         // 8 blocks of a batch: same XCD class
    const int c  = blockIdx.x >> 7;          // 0..7
    const int w  = threadIdx.x >> 6;
    const int lt = threadIdx.x & 63;
    const int dir  = w & 1;
    const int half = w >> 1;

    if (blockIdx.x == 0 && threadIdx.x == 0) out[0] = 0.0f;  // delete memset dispatch

    __shared__ unsigned sxy[4][JCH];         // half2 (qx,qy), wave-private
    __shared__ unsigned szz[4][JCH];         // half2 (qz, 0)
    __shared__ float    sq2[4][JCH];         // |q_hat|^2 fp32
    __shared__ float comb[2][NUM_PTS + 64];  // stride-17 combine buffer

    // --- stage this wave's 64-pt q sub-chunk, quantized to f16
    {
        const float* qsrc = (dir == 0 ? recon_x : x)
            + (size_t)b * NUM_PTS * 3 + (size_t)(c * 128 + half * JCH + lt) * 3;
        const _Float16 hx = (_Float16)qsrc[0];
        const _Float16 hy = (_Float16)qsrc[1];
        const _Float16 hz = (_Float16)qsrc[2];
        const float fx = (float)hx, fy = (float)hy, fz = (float)hz;
        h2 xy; xy.x = hx; xy.y = hy;
        h2 z0; z0.x = hz; z0.y = (_Float16)0.0f;
        sxy[w][lt] = as_u32(xy);
        szz[w][lt] = as_u32(z0);
        sq2[w][lt] = fmaf(fx, fx, fmaf(fy, fy, fz * fz));
    }

    // --- own 16 contiguous rows: quantize, keep A = -2*p_hat (half2) + r2 fp32
    const float* rp = (dir == 0 ? x : recon_x) + (size_t)b * NUM_PTS * 3;
    h2 Axy[R], Az0[R];
    float r2[R], m[R];
    {
        float buf[48];
        const float4* __restrict__ s4 = (const float4*)(rp + 48 * lt);
        float4* bp = (float4*)buf;
#pragma unroll
        for (int i = 0; i < 12; ++i) bp[i] = s4[i];
#pragma unroll
        for (int k = 0; k < R; ++k) {
            const _Float16 hx = (_Float16)buf[3 * k + 0];
            const _Float16 hy = (_Float16)buf[3 * k + 1];
            const _Float16 hz = (_Float16)buf[3 * k + 2];
            const float fx = (float)hx, fy = (float)hy, fz = (float)hz;
            r2[k] = fmaf(fx, fx, fmaf(fy, fy, fz * fz));
            Axy[k].x = (_Float16)-2.0f * hx;   // exact: x2 in f16
            Axy[k].y = (_Float16)-2.0f * hy;
            Az0[k].x = (_Float16)-2.0f * hz;
            Az0[k].y = (_Float16)0.0f;
            m[k] = 1e30f;
        }
    }

    // --- 16 groups x 4 qpts: per eval 2 x v_dot2_f32_f16, min3 per pair
    const uint4*  __restrict__ xyp = (const uint4*)sxy[w];
    const uint4*  __restrict__ zzp = (const uint4*)szz[w];
    const float4* __restrict__ q2p = (const float4*)sq2[w];
#pragma unroll 2
    for (int g = 0; g < JCH / 4; ++g) {
        const uint4  XY = xyp[g];
        const uint4  ZZ = zzp[g];
        const float4 Q2 = q2p[g];
        const h2 xy0 = as_h2(XY.x), xy1 = as_h2(XY.y), xy2 = as_h2(XY.z), xy3 = as_h2(XY.w);
        const h2 zz0 = as_h2(ZZ.x), zz1 = as_h2(ZZ.y), zz2 = as_h2(ZZ.z), zz3 = as_h2(ZZ.w);
#pragma unroll
        for (int r = 0; r < R; ++r) {
            float d0 = __builtin_amdgcn_fdot2(Az0[r], zz0, Q2.x, false);
            d0 = __builtin_amdgcn_fdot2(Axy[r], xy0, d0, false);
            float d1 = __builtin_amdgcn_fdot2(Az0[r], zz1, Q2.y, false);
            d1 = __builtin_amdgcn_fdot2(Axy[r], xy1, d1, false);
            m[r] = fminf(fminf(m[r], d0), d1);            // v_min3_f32
        }
#pragma unroll
        for (int r = 0; r < R; ++r) {
            float d2 = __builtin_amdgcn_fdot2(Az0[r], zz2, Q2.z, false);
            d2 = __builtin_amdgcn_fdot2(Axy[r], xy2, d2, false);
            float d3 = __builtin_amdgcn_fdot2(Az0[r], zz3, Q2.w, false);
            d3 = __builtin_amdgcn_fdot2(Axy[r], xy3, d3, false);
            m[r] = fminf(fminf(m[r], d2), d3);
        }
    }

    // --- combine q-halves (stride 17 => free 2-way bank aliasing only)
    if (half == 0) {
#pragma unroll
        for (int k = 0; k < R; ++k)
            comb[dir][17 * lt + k] = m[k];
    }
    __syncthreads();
    if (half == 1) {
        float4* dst = (float4*)(ws + (size_t)dir * WS_DIR + (size_t)c * WS_CHUNK
                                + b * NUM_PTS + 16 * lt);
#pragma unroll
        for (int k4 = 0; k4 < 4; ++k4) {
            float o[4];
#pragma unroll
            for (int i = 0; i < 4; ++i) {
                const int k = 4 * k4 + i;
                o[i] = r2[k] + fminf(m[k], comb[dir][17 * lt + k]);
            }
            dst[k4] = make_float4(o[0], o[1], o[2], o[3]);
        }
    }
}

// Fold 8 chunk partials per row (4 rows/thread via float4), sum, fold KLD.
__global__ __launch_bounds__(RT) void reduce_kernel(
    const float* __restrict__ ws,
    const float* __restrict__ mu,
    const float* __restrict__ logvar,
    float* __restrict__ out)
{
    const int gid  = blockIdx.x * RT + threadIdx.x;   // 0..65535
    const int base = gid * 4;
    const int dir  = base >> 17;
    const int rem  = base & 131071;                   // b*1024 + row

    const float4* p = (const float4*)(ws + (size_t)dir * WS_DIR + rem);
    float4 mn = p[0];
#pragma unroll
    for (int c = 1; c < NJC; ++c) {
        const float4 q = p[c * (WS_CHUNK / 4)];
        mn.x = fminf(mn.x, q.x);
        mn.y = fminf(mn.y, q.y);
        mn.z = fminf(mn.z, q.z);
        mn.w = fminf(mn.w, q.w);
    }
    float v = (mn.x + mn.y + mn.z + mn.w) * CHAMF_SCALE;

    if (blockIdx.x < 16) {                            // 16*256 = 4096 latents
        const int t = blockIdx.x * RT + threadIdx.x;
        const float lv = logvar[t];
        const float mm = mu[t];
        v += (1.0f + lv - mm * mm - expf(lv)) * KLD_SCALE;
    }

    for (int off = 32; off > 0; off >>= 1)
        v += __shfl_down(v, off, 64);

    __shared__ float red[RT / 64];
    const int lane = threadIdx.x & 63;
    const int wv   = threadIdx.x >> 6;
    if (lane == 0) red[wv] = v;
    __syncthreads();
    if (threadIdx.x == 0) {
        float sum = 0.f;
        for (int wq = 0; wq < RT / 64; ++wq) sum += red[wq];
        atomicAdd(out, sum);
    }
}

extern "C" void kernel_launch(void* const* d_in, const int* in_sizes, int n_in,
                              void* d_out, int out_size, void* d_ws, size_t ws_size,
                              hipStream_t stream) {
    const float* recon_x = (const float*)d_in[0];
    const float* x       = (const float*)d_in[1];
    const float* mu      = (const float*)d_in[2];
    const float* logvar  = (const float*)d_in[3];
    float* out = (float*)d_out;
    float* ws  = (float*)d_ws;            // needs 8.4 MB

    chamfer_part<<<NBATCH * NJC, BT, 0, stream>>>(recon_x, x, ws, out);
    reduce_kernel<<<256, RT, 0, stream>>>(ws, mu, logvar, out);
}

// Round 17
// 86.601 us; speedup vs baseline: 1.0833x; 1.0833x over previous
//
#include <hip/hip_runtime.h>

#define NUM_PTS 1024
#define NBATCH 128
#define BT 256                       // 4 waves: w = dir + 2*qhalf
#define RT 256
#define NJC 8                        // stored q-chunks per direction (128 pts each)
#define JCH 64                       // points per wave (half chunk)
#define R 16                         // rows per thread (64 lanes x 16 = all 1024)
#define CHAMF_SCALE (1.0f / 1024.0f)
#define KLD_SCALE   (-0.5f * 0.1f / 32.0f)

// ws: float [2][NJC][NBATCH][NUM_PTS] row partials = 8.4 MB.
#define WS_CHUNK (NBATCH * NUM_PTS)          // 131072
#define WS_DIR   (NJC * WS_CHUNK)            // 1048576

// R14 exact revert (best known: 87.6 us). fp32 inner loop: 3 fma + 0.5 min3
// per eval. Both "cheaper math" attempts failed on HW: pk_fp32 is
// rate-neutral (R4), v_dot2_f32_f16 regressed +6us (R15: same issue rate as
// fma, +120 cvt/pack prologue insts, register-shuffle tax). 3.5 insts/eval
// IS the floor for this op on CDNA4 (no fp32 MFMA; f16-MFMA epilogue costs
// more than it saves).
__global__ __launch_bounds__(BT, 2) void chamfer_part(
    const float* __restrict__ recon_x,
    const float* __restrict__ x,
    float* __restrict__ ws,
    float* __restrict__ out)
{
    const int b  = blockIdx.x & 127;         // 8 blocks of a batch: same XCD class
    const int c  = blockIdx.x >> 7;          // 0..7
    const int w  = threadIdx.x >> 6;
    const int lt = threadIdx.x & 63;
    const int dir  = w & 1;
    const int half = w >> 1;

    if (blockIdx.x == 0 && threadIdx.x == 0) out[0] = 0.0f;  // delete memset dispatch

    __shared__ float sq[4][4][JCH];          // wave-private q planes, 4 KB
    __shared__ float comb[2][NUM_PTS + 64];  // stride-17 combine buffer, 8.5 KB

    // --- stage this wave's 64-pt q sub-chunk (wave-private: no barrier)
    {
        const float* qsrc = (dir == 0 ? recon_x : x)
            + (size_t)b * NUM_PTS * 3 + (size_t)(c * 128 + half * JCH + lt) * 3;
        const float qx = qsrc[0], qy = qsrc[1], qz = qsrc[2];
        sq[w][0][lt] = qx;
        sq[w][1][lt] = qy;
        sq[w][2][lt] = qz;
        sq[w][3][lt] = fmaf(qx, qx, fmaf(qy, qy, qz * qz));
    }

    // --- own 16 contiguous rows: 12 coalesced float4 loads, keep -2*coord
    const float* rp = (dir == 0 ? x : recon_x) + (size_t)b * NUM_PTS * 3;
    float vx[R], vy[R], vz[R], m[R];
    {
        float buf[48];
        const float4* __restrict__ s4 = (const float4*)(rp + 48 * lt);
        float4* bp = (float4*)buf;
#pragma unroll
        for (int i = 0; i < 12; ++i) bp[i] = s4[i];
#pragma unroll
        for (int k = 0; k < R; ++k) {
            vx[k] = -2.0f * buf[3 * k + 0];
            vy[k] = -2.0f * buf[3 * k + 1];
            vz[k] = -2.0f * buf[3 * k + 2];
            m[k]  = 1e30f;
        }
    }

    // --- 16 groups x 4 qpts over this wave's sub-chunk
    const float4* __restrict__ qxp = (const float4*)sq[w][0];
    const float4* __restrict__ qyp = (const float4*)sq[w][1];
    const float4* __restrict__ qzp = (const float4*)sq[w][2];
    const float4* __restrict__ q2p = (const float4*)sq[w][3];
#pragma unroll 2
    for (int g = 0; g < JCH / 4; ++g) {
        const float4 qx = qxp[g];
        const float4 qy = qyp[g];
        const float4 qz = qzp[g];
        const float4 q2 = q2p[g];
#pragma unroll
        for (int r = 0; r < R; ++r) {
            const float d0 = fmaf(vx[r], qx.x, fmaf(vy[r], qy.x, fmaf(vz[r], qz.x, q2.x)));
            const float d1 = fmaf(vx[r], qx.y, fmaf(vy[r], qy.y, fmaf(vz[r], qz.y, q2.y)));
            m[r] = fminf(fminf(m[r], d0), d1);            // v_min3_f32
        }
#pragma unroll
        for (int r = 0; r < R; ++r) {
            const float d2 = fmaf(vx[r], qx.z, fmaf(vy[r], qy.z, fmaf(vz[r], qz.z, q2.z)));
            const float d3 = fmaf(vx[r], qx.w, fmaf(vy[r], qy.w, fmaf(vz[r], qz.w, q2.w)));
            m[r] = fminf(fminf(m[r], d2), d3);
        }
    }

    // --- combine q-halves (stride 17 => only free 2-way bank aliasing)
    if (half == 0) {
#pragma unroll
        for (int k = 0; k < R; ++k)
            comb[dir][17 * lt + k] = m[k];
    }
    __syncthreads();
    if (half == 1) {
        float4* dst = (float4*)(ws + (size_t)dir * WS_DIR + (size_t)c * WS_CHUNK
                                + b * NUM_PTS + 16 * lt);
#pragma unroll
        for (int k4 = 0; k4 < 4; ++k4) {
            float o[4];
#pragma unroll
            for (int i = 0; i < 4; ++i) {
                const int k = 4 * k4 + i;
                const float mm = fminf(m[k], comb[dir][17 * lt + k]);
                const float r2 = 0.25f * fmaf(vx[k], vx[k],
                                        fmaf(vy[k], vy[k], vz[k] * vz[k]));
                o[i] = r2 + mm;
            }
            dst[k4] = make_float4(o[0], o[1], o[2], o[3]);
        }
    }
}

// Fold 8 chunk partials per row (4 rows/thread via float4), sum, fold KLD.
// 256 blocks x 256 threads cover 2 x 128 x 1024 row slots.
__global__ __launch_bounds__(RT) void reduce_kernel(
    const float* __restrict__ ws,
    const float* __restrict__ mu,
    const float* __restrict__ logvar,
    float* __restrict__ out)
{
    const int gid  = blockIdx.x * RT + threadIdx.x;   // 0..65535
    const int base = gid * 4;
    const int dir  = base >> 17;
    const int rem  = base & 131071;                   // b*1024 + row

    const float4* p = (const float4*)(ws + (size_t)dir * WS_DIR + rem);
    float4 mn = p[0];
#pragma unroll
    for (int c = 1; c < NJC; ++c) {
        const float4 q = p[c * (WS_CHUNK / 4)];
        mn.x = fminf(mn.x, q.x);
        mn.y = fminf(mn.y, q.y);
        mn.z = fminf(mn.z, q.z);
        mn.w = fminf(mn.w, q.w);
    }
    float v = (mn.x + mn.y + mn.z + mn.w) * CHAMF_SCALE;

    if (blockIdx.x < 16) {                            // 16*256 = 4096 latents
        const int t = blockIdx.x * RT + threadIdx.x;
        const float lv = logvar[t];
        const float mm = mu[t];
        v += (1.0f + lv - mm * mm - expf(lv)) * KLD_SCALE;
    }

    for (int off = 32; off > 0; off >>= 1)
        v += __shfl_down(v, off, 64);

    __shared__ float red[RT / 64];
    const int lane = threadIdx.x & 63;
    const int wv   = threadIdx.x >> 6;
    if (lane == 0) red[wv] = v;
    __syncthreads();
    if (threadIdx.x == 0) {
        float sum = 0.f;
        for (int wq = 0; wq < RT / 64; ++wq) sum += red[wq];
        atomicAdd(out, sum);
    }
}

extern "C" void kernel_launch(void* const* d_in, const int* in_sizes, int n_in,
                              void* d_out, int out_size, void* d_ws, size_t ws_size,
                              hipStream_t stream) {
    const float* recon_x = (const float*)d_in[0];
    const float* x       = (const float*)d_in[1];
    const float* mu      = (const float*)d_in[2];
    const float* logvar  = (const float*)d_in[3];
    float* out = (float*)d_out;
    float* ws  = (float*)d_ws;            // needs 8.4 MB

    chamfer_part<<<NBATCH * NJC, BT, 0, stream>>>(recon_x, x, ws, out);
    reduce_kernel<<<256, RT, 0, stream>>>(ws, mu, logvar, out);
}